// Round 18
// baseline (32.137 us; speedup 1.0000x reference)
//
#include <hip/hip_runtime.h>
#include <hip/hip_bf16.h>

// TT embedding: vocab 65536, dim 1024, rank 16.
// out[v,d] = sum_{r1..r4} c0[0,i0,r1] c1[r1,i1,r2] c2[r2,i2,r3] c3[r3,i3,r4] c4[r4,i4,0]
//   i0=v>>11, i1=(v>>6)&31, i2=(v>>1)&31, i3=(v&1)*16+(d>>6), i4=d&63
//
// R17 lesson: scalar path is pinned at ~24us = SUM(L1-lines 11 + LDS 7 +
// VALU 5.6) per CU; 7 schedule rewrites moved it 2us. R18 changes the
// ALGORITHM: precompute M[k=r3+16*b][d] = sum_r4 c3[r3][b*16+d1][r4]*c4[r4][i4]
// (32x1024, 64KB bf16, shared by ALL tokens), then
//   out[token] = w3ext[token] (1x32, zeros in the non-vlow half) x M
// batched 16 tokens/wave via v_mfma_f32_16x16x32_bf16:
//   A = M-tile (16d x 32k), B = w3ext (32k x 16tok), D: row=d, col=token.
// Fragment mapping used (written by K1, read by K3 -> only HW mapping must
// match): lane l, elem i: k = 4*(l>>4) + (i&3) + 16*(i>>2); row/col = l&15.
// C/D: col=lane&15, row=(lane>>4)*4+reg  [HW-verified, m89].
// Per token: ~65 L1 lines (was 420), ~40 VALU (was 420). bf16 quant error
// ~5e-10 << 5.5e-9 threshold (fp16-c4 probe R13 measured 9.3e-10).

typedef float f32x4 __attribute__((ext_vector_type(4)));
typedef short bf16x8 __attribute__((ext_vector_type(8)));
typedef short s16x4 __attribute__((ext_vector_type(4)));

static __device__ __forceinline__ unsigned short f2bf(float x) {
    __hip_bfloat16 h = __float2bfloat16(x);
    return *reinterpret_cast<unsigned short*>(&h);
}

// ---------------- K1: Mfrag precompute (32768 elements) ----------------
// mfrag flat index = tile*512 + lane*8 + i  holds  M[k(lane,i)][d(tile,lane)]
__global__ __launch_bounds__(256) void tt_mfrag(
    const float* __restrict__ c3,   // 16*32*16
    const float* __restrict__ c4,   // 16*64
    unsigned short* __restrict__ mfrag)
{
    const int tid  = blockIdx.x * 256 + threadIdx.x;   // 0..32767
    const int tile = tid >> 9;
    const int lane = (tid >> 3) & 63;
    const int i    = tid & 7;
    const int k = 4 * (lane >> 4) + (i & 3) + ((i >> 2) << 4);
    const int d = (tile << 4) + (lane & 15);
    const int r3 = k & 15;
    const int b  = k >> 4;
    const int i3 = (b << 4) + (d >> 6);
    const int i4 = d & 63;
    float acc = 0.f;
    #pragma unroll
    for (int r4 = 0; r4 < 16; ++r4)
        acc = fmaf(c3[(r3 * 32 + i3) * 16 + r4], c4[(r4 << 6) + i4], acc);
    mfrag[tid] = f2bf(acc);
}

// ---------------- K2: stages 1-2 -> w3ext bf16 rows (32 ushorts/token) ----
__global__ __launch_bounds__(256) void tt_w3(
    const float* __restrict__ c0, const float* __restrict__ c1,
    const float* __restrict__ c2, const int* __restrict__ idx,
    unsigned int* __restrict__ w3x, int n_tokens)
{
    const int t = threadIdx.x;
    const int tl = t >> 4;           // token slot (16/block)
    const int r  = t & 15;
    const int token = blockIdx.x * 16 + tl;
    const int v = (token < n_tokens) ? idx[token] : 0;

    __shared__ float w2b[16][20];
    __shared__ float w3b[16][20];

    // Stage 1
    {
        const int i0 = (v >> 11) & 31;
        const int i1 = (v >> 6) & 31;
        float w2r = 0.f;
        #pragma unroll
        for (int r1 = 0; r1 < 16; ++r1)
            w2r = fmaf(c0[i0 * 16 + r1], c1[(r1 * 32 + i1) * 16 + r], w2r);
        w2b[tl][r] = w2r;            // same 16-lane group = same wave: no barrier
    }
    float4 w2v[4];
    #pragma unroll
    for (int q = 0; q < 4; ++q)
        w2v[q] = *(const float4*)&w2b[tl][q << 2];

    // Stage 2 (r2 order 0..15)
    {
        const int i2 = (v >> 1) & 31;
        float w3r = 0.f;
        #pragma unroll
        for (int q = 0; q < 4; ++q) {
            w3r = fmaf(w2v[q].x, c2[((q * 4 + 0) * 32 + i2) * 16 + r], w3r);
            w3r = fmaf(w2v[q].y, c2[((q * 4 + 1) * 32 + i2) * 16 + r], w3r);
            w3r = fmaf(w2v[q].z, c2[((q * 4 + 2) * 32 + i2) * 16 + r], w3r);
            w3r = fmaf(w2v[q].w, c2[((q * 4 + 3) * 32 + i2) * 16 + r], w3r);
        }
        w3b[tl][r] = w3r;
    }

    // Pack w3ext row: k in [vlow*16, vlow*16+16) -> bf16(w3[k&15]), else 0.
    {
        const int vlow = v & 1;
        const int k0 = 2 * r, k1 = 2 * r + 1;
        const float f0 = w3b[tl][k0 & 15];
        const float f1 = w3b[tl][k1 & 15];
        const unsigned int lo = ((k0 >> 4) == vlow) ? f2bf(f0) : 0u;
        const unsigned int hi = ((k1 >> 4) == vlow) ? f2bf(f1) : 0u;
        if (token < n_tokens)
            w3x[token * 16 + r] = lo | (hi << 16);
    }
}

// ---------------- K3: MFMA expand. 1 block = 16 tokens; wave w = d-quarter --
__global__ __launch_bounds__(256) void tt_expand(
    const unsigned short* __restrict__ mfrag,
    const unsigned short* __restrict__ w3x,
    float* __restrict__ out, int n_tokens)
{
    const int t = threadIdx.x;
    const int w = t >> 6;            // wave: d-quarter
    const int l = t & 63;
    const int col = l & 15;          // token within group
    const int g   = l >> 4;
    const int tg  = blockIdx.x;

    const int token = tg * 16 + col;
    const int tokc  = (token < n_tokens) ? token : (n_tokens - 1);
    const bool ok   = (token < n_tokens);

    // B fragment: w3ext[token][k], k = 4g+{0..3} and 16+4g+{0..3}
    const unsigned short* wrow = w3x + (size_t)tokc * 32;
    const s16x4 blo = *(const s16x4*)(wrow + 4 * g);
    const s16x4 bhi = *(const s16x4*)(wrow + 16 + 4 * g);
    const bf16x8 bf = {blo.x, blo.y, blo.z, blo.w, bhi.x, bhi.y, bhi.z, bhi.w};

    float* outp = out + (size_t)token * 1024 + (g << 2);

    #pragma unroll
    for (int n = 0; n < 16; ++n) {
        const int T = w * 16 + n;    // global d-tile
        const bf16x8 af = *(const bf16x8*)(mfrag + (size_t)T * 512 + l * 8);
        f32x4 acc = {0.f, 0.f, 0.f, 0.f};
        acc = __builtin_amdgcn_mfma_f32_16x16x32_bf16(af, bf, acc, 0, 0, 0);
        if (ok)
            __builtin_nontemporal_store(acc, (f32x4*)(outp + (T << 4)));
    }
}

// ---------------- Fallback: R16 fused scalar kernel (proven 25.6us) --------
#define RSTRIDE 20
#define GSTRIDE 328

__global__ __launch_bounds__(256) void tt_embed_fused(
    const float* __restrict__ c0, const float* __restrict__ c1,
    const float* __restrict__ c2, const float* __restrict__ c3,
    const float* __restrict__ c4, const int* __restrict__ idx,
    float* __restrict__ out, int n_tokens)
{
    const int t   = threadIdx.x;
    const int tl  = t >> 5;
    const int l32 = t & 31;
    const int r   = t & 15;
    const int l   = t & 63;
    const int wid = t >> 6;
    const int token = blockIdx.x * 8 + tl;
    const int v = (token < n_tokens) ? idx[token] : 0;

    __shared__ float w4s[8 * GSTRIDE];
    __shared__ float w2b[8][20];
    __shared__ float w3b[8][20];

    float4 c4v[16];
    #pragma unroll
    for (int r4 = 0; r4 < 16; ++r4)
        c4v[r4] = *(const float4*)(c4 + (r4 << 6) + ((l & 15) << 2));

    {
        const int i0 = (v >> 11) & 31, i1 = (v >> 6) & 31;
        float w2r = 0.f;
        #pragma unroll
        for (int r1 = 0; r1 < 16; ++r1)
            w2r = fmaf(c0[i0 * 16 + r1], c1[(r1 * 32 + i1) * 16 + r], w2r);
        w2b[tl][r] = w2r;
    }
    float4 w2v[4];
    #pragma unroll
    for (int q = 0; q < 4; ++q)
        w2v[q] = *(const float4*)&w2b[tl][q << 2];
    {
        const int i2 = (v >> 1) & 31;
        float w3r = 0.f;
        #pragma unroll
        for (int q = 0; q < 4; ++q) {
            w3r = fmaf(w2v[q].x, c2[((q * 4 + 0) * 32 + i2) * 16 + r], w3r);
            w3r = fmaf(w2v[q].y, c2[((q * 4 + 1) * 32 + i2) * 16 + r], w3r);
            w3r = fmaf(w2v[q].z, c2[((q * 4 + 2) * 32 + i2) * 16 + r], w3r);
            w3r = fmaf(w2v[q].w, c2[((q * 4 + 3) * 32 + i2) * 16 + r], w3r);
        }
        w3b[tl][r] = w3r;
    }
    float4 w3v[4];
    #pragma unroll
    for (int q = 0; q < 4; ++q)
        w3v[q] = *(const float4*)&w3b[tl][q << 2];
    {
        const int vlow16 = (v & 1) << 4;
        float4 a0 = {0,0,0,0}, a1 = {0,0,0,0};
        const float wv_arr0[16] = {w3v[0].x, w3v[0].y, w3v[0].z, w3v[0].w,
                                   w3v[1].x, w3v[1].y, w3v[1].z, w3v[1].w,
                                   w3v[2].x, w3v[2].y, w3v[2].z, w3v[2].w,
                                   w3v[3].x, w3v[3].y, w3v[3].z, w3v[3].w};
        #pragma unroll
        for (int r3 = 0; r3 < 16; ++r3) {
            const float wv = wv_arr0[r3];
            const float* base = c3 + ((r3 * 32 + vlow16) << 4);
            const float4 b0 = *(const float4*)(base + (l32 << 2));
            const float4 b1 = *(const float4*)(base + 128 + (l32 << 2));
            a0.x = fmaf(wv, b0.x, a0.x); a0.y = fmaf(wv, b0.y, a0.y);
            a0.z = fmaf(wv, b0.z, a0.z); a0.w = fmaf(wv, b0.w, a0.w);
            a1.x = fmaf(wv, b1.x, a1.x); a1.y = fmaf(wv, b1.y, a1.y);
            a1.z = fmaf(wv, b1.z, a1.z); a1.w = fmaf(wv, b1.w, a1.w);
        }
        float* sb = &w4s[tl * GSTRIDE + ((l32 & 3) << 2)];
        *(float4*)(sb + ((l32 >> 2)    ) * RSTRIDE) = a0;
        *(float4*)(sb + (8 + (l32 >> 2)) * RSTRIDE) = a1;
    }
    #pragma unroll
    for (int s = 0; s < 2; ++s) {
        const int slot = 2 * wid + s;
        const int tok  = blockIdx.x * 8 + slot;
        const float* slab = &w4s[slot * GSTRIDE];
        const int sub = l >> 4;
        const int colb = (l & 15) << 2;
        #pragma unroll
        for (int j = 0; j < 4; ++j) {
            const int row = (j << 2) + sub;
            const float* rp = slab + row * RSTRIDE;
            const float4 wa = *(const float4*)(rp);
            const float4 wb = *(const float4*)(rp + 4);
            const float4 wc = *(const float4*)(rp + 8);
            const float4 wd = *(const float4*)(rp + 12);
            float4 acc = {0,0,0,0};
            #define FB4(WV, K)                           \
                acc.x = fmaf(WV, c4v[K].x, acc.x);       \
                acc.y = fmaf(WV, c4v[K].y, acc.y);       \
                acc.z = fmaf(WV, c4v[K].z, acc.z);       \
                acc.w = fmaf(WV, c4v[K].w, acc.w);
            FB4(wa.x,  0) FB4(wa.y,  1) FB4(wa.z,  2) FB4(wa.w,  3)
            FB4(wb.x,  4) FB4(wb.y,  5) FB4(wb.z,  6) FB4(wb.w,  7)
            FB4(wc.x,  8) FB4(wc.y,  9) FB4(wc.z, 10) FB4(wc.w, 11)
            FB4(wd.x, 12) FB4(wd.y, 13) FB4(wd.z, 14) FB4(wd.w, 15)
            #undef FB4
            if (tok < n_tokens)
                __builtin_nontemporal_store(*(const f32x4*)&acc,
                    (f32x4*)(out + (size_t)tok * 1024 + (row << 6) + colb));
        }
    }
}

extern "C" void kernel_launch(void* const* d_in, const int* in_sizes, int n_in,
                              void* d_out, int out_size, void* d_ws, size_t ws_size,
                              hipStream_t stream) {
    const float* c0  = (const float*)d_in[0];
    const float* c1  = (const float*)d_in[1];
    const float* c2  = (const float*)d_in[2];
    const float* c3  = (const float*)d_in[3];
    const float* c4  = (const float*)d_in[4];
    const int*   idx = (const int*)d_in[5];
    float* out = (float*)d_out;

    const int n_tokens = in_sizes[5];                       // 16384
    const size_t ws_needed = 65536 + (size_t)n_tokens * 64 + 256;

    if (ws_size >= ws_needed) {
        unsigned short* mfrag = (unsigned short*)d_ws;
        unsigned int*   w3x   = (unsigned int*)((char*)d_ws + 65536);
        const int ngrp = (n_tokens + 15) / 16;              // 1024
        tt_mfrag<<<128, 256, 0, stream>>>(c3, c4, mfrag);
        tt_w3<<<ngrp, 256, 0, stream>>>(c0, c1, c2, idx, w3x, n_tokens);
        tt_expand<<<ngrp, 256, 0, stream>>>(mfrag, (const unsigned short*)w3x,
                                            out, n_tokens);
    } else {
        const int grid = (n_tokens + 7) / 8;
        tt_embed_fused<<<grid, 256, 0, stream>>>(c0, c1, c2, c3, c4, idx, out,
                                                 n_tokens);
    }
}

// Round 19
// 30.087 us; speedup vs baseline: 1.0681x; 1.0681x over previous
//
#include <hip/hip_runtime.h>
#include <hip/hip_bf16.h>

// TT embedding: vocab 65536, dim 1024, rank 16.
// out[v,d] = sum_{r1..r4} c0[0,i0,r1] c1[r1,i1,r2] c2[r2,i2,r3] c3[r3,i3,r4] c4[r4,i4,0]
//   i0=v>>11, i1=(v>>6)&31, i2=(v>>1)&31, i3=(v&1)*16+(d>>6), i4=d&63
//
// R18 proved the MFMA algorithm (absmax 9.3e-10 = bf16 quant, correct
// fragment mapping) but 3 serialized dispatches + w3x HBM round-trip cost
// more than the algorithm saved. R19 fuses K2+K3:
//   K1 (unchanged): mfrag[tile*512 + lane*8 + i] = bf16(M[k(lane,i)][d]),
//       M = c3 x c4 contraction, 64KB, shared by all tokens, L2-resident.
//   K2' (fused): block = 16 tokens.
//       phase A: stages 1-2 (16-lane groups, wave-local LDS round-trips),
//                pack w3ext bf16 pairs into LDS uints w3e[16][18] (pad 18 ->
//                conflict-free b64 B-fragment reads, 8B-aligned).
//       barrier (the only one)
//       phase B: wave w = d-quarter; 16x { A-frag 1KB coalesced from mfrag,
//                v_mfma_f32_16x16x32_bf16, 16-line full-line store }.
// Per token: ~65 L1 lines, ~40 VALU, 1 MFMA/4 d-tiles. bf16 error 9.3e-10
// << 5.48e-9 threshold (measured R18).

typedef float f32x4 __attribute__((ext_vector_type(4)));
typedef short bf16x8 __attribute__((ext_vector_type(8)));
typedef short s16x4 __attribute__((ext_vector_type(4)));
typedef unsigned int uint2v __attribute__((ext_vector_type(2)));

static __device__ __forceinline__ unsigned short f2bf(float x) {
    __hip_bfloat16 h = __float2bfloat16(x);
    return *reinterpret_cast<unsigned short*>(&h);
}

// ---------------- K1: Mfrag precompute (32768 elements) ----------------
__global__ __launch_bounds__(256) void tt_mfrag(
    const float* __restrict__ c3,   // 16*32*16
    const float* __restrict__ c4,   // 16*64
    unsigned short* __restrict__ mfrag)
{
    const int tid  = blockIdx.x * 256 + threadIdx.x;   // 0..32767
    const int tile = tid >> 9;
    const int lane = (tid >> 3) & 63;
    const int i    = tid & 7;
    const int k = 4 * (lane >> 4) + (i & 3) + ((i >> 2) << 4);
    const int d = (tile << 4) + (lane & 15);
    const int r3 = k & 15;
    const int b  = k >> 4;
    const int i3 = (b << 4) + (d >> 6);
    const int i4 = d & 63;
    float acc = 0.f;
    #pragma unroll
    for (int r4 = 0; r4 < 16; ++r4)
        acc = fmaf(c3[(r3 * 32 + i3) * 16 + r4], c4[(r4 << 6) + i4], acc);
    mfrag[tid] = f2bf(acc);
}

// ---------------- K2': fused stages1-2 + MFMA expand ----------------
__global__ __launch_bounds__(256) void tt_fused_expand(
    const float* __restrict__ c0, const float* __restrict__ c1,
    const float* __restrict__ c2, const int* __restrict__ idx,
    const unsigned short* __restrict__ mfrag,
    float* __restrict__ out, int n_tokens)
{
    const int t  = threadIdx.x;
    const int tl = t >> 4;           // token slot (16/block), phase A
    const int r  = t & 15;
    const int token = blockIdx.x * 16 + tl;
    const int v = (token < n_tokens) ? idx[token] : 0;

    __shared__ float w2b[16][20];
    __shared__ float w3b[16][20];
    __shared__ unsigned int w3e[16][18];   // packed bf16 pairs, pad 18

    // ---- phase A: stages 1-2 (wave-local; no barriers inside)
    {
        const int i0 = (v >> 11) & 31;
        const int i1 = (v >> 6) & 31;
        float w2r = 0.f;
        #pragma unroll
        for (int r1 = 0; r1 < 16; ++r1)
            w2r = fmaf(c0[i0 * 16 + r1], c1[(r1 * 32 + i1) * 16 + r], w2r);
        w2b[tl][r] = w2r;            // 16-lane group lives in one wave
    }
    float4 w2v[4];
    #pragma unroll
    for (int q = 0; q < 4; ++q)
        w2v[q] = *(const float4*)&w2b[tl][q << 2];

    {
        const int i2 = (v >> 1) & 31;
        float w3r = 0.f;
        #pragma unroll
        for (int q = 0; q < 4; ++q) {
            w3r = fmaf(w2v[q].x, c2[((q * 4 + 0) * 32 + i2) * 16 + r], w3r);
            w3r = fmaf(w2v[q].y, c2[((q * 4 + 1) * 32 + i2) * 16 + r], w3r);
            w3r = fmaf(w2v[q].z, c2[((q * 4 + 2) * 32 + i2) * 16 + r], w3r);
            w3r = fmaf(w2v[q].w, c2[((q * 4 + 3) * 32 + i2) * 16 + r], w3r);
        }
        w3b[tl][r] = w3r;
    }
    // pack w3ext row into LDS: uint r holds bf16(k=2r) | bf16(k=2r+1)<<16,
    // zeroed outside the token's vlow half.
    {
        const int vlow = v & 1;
        const int k0 = 2 * r, k1 = 2 * r + 1;
        const float f0 = w3b[tl][k0 & 15];
        const float f1 = w3b[tl][k1 & 15];
        const unsigned int lo = ((k0 >> 4) == vlow) ? f2bf(f0) : 0u;
        const unsigned int hi = ((k1 >> 4) == vlow) ? f2bf(f1) : 0u;
        w3e[tl][r] = lo | (hi << 16);
    }

    __syncthreads();   // the only barrier

    // ---- phase B: MFMA expand. wave w = d-quarter; lane: col=token, g=row grp
    {
        const int w   = t >> 6;
        const int l   = t & 63;
        const int col = l & 15;
        const int g   = l >> 4;

        const int tok = blockIdx.x * 16 + col;
        const bool ok = (tok < n_tokens);

        // B fragment from LDS: k = 4g..4g+3 (uints 2g,2g+1), 16+4g..+3 (8+2g,+1)
        const uint2v ulo = *(const uint2v*)&w3e[col][2 * g];
        const uint2v uhi = *(const uint2v*)&w3e[col][8 + 2 * g];
        const s16x4 blo = *(const s16x4*)&ulo;
        const s16x4 bhi = *(const s16x4*)&uhi;
        const bf16x8 bf = {blo.x, blo.y, blo.z, blo.w,
                           bhi.x, bhi.y, bhi.z, bhi.w};

        float* outp = out + (size_t)tok * 1024 + (g << 2);

        #pragma unroll
        for (int n = 0; n < 16; ++n) {
            const int T = w * 16 + n;    // global d-tile
            const bf16x8 af = *(const bf16x8*)(mfrag + (size_t)T * 512 + l * 8);
            f32x4 acc = {0.f, 0.f, 0.f, 0.f};
            acc = __builtin_amdgcn_mfma_f32_16x16x32_bf16(af, bf, acc, 0, 0, 0);
            if (ok)
                __builtin_nontemporal_store(acc, (f32x4*)(outp + (T << 4)));
        }
    }
}

// ---------------- Fallback: R16 fused scalar kernel (proven 25.6us) --------
#define RSTRIDE 20
#define GSTRIDE 328

__global__ __launch_bounds__(256) void tt_embed_fused(
    const float* __restrict__ c0, const float* __restrict__ c1,
    const float* __restrict__ c2, const float* __restrict__ c3,
    const float* __restrict__ c4, const int* __restrict__ idx,
    float* __restrict__ out, int n_tokens)
{
    const int t   = threadIdx.x;
    const int tl  = t >> 5;
    const int l32 = t & 31;
    const int r   = t & 15;
    const int l   = t & 63;
    const int wid = t >> 6;
    const int token = blockIdx.x * 8 + tl;
    const int v = (token < n_tokens) ? idx[token] : 0;

    __shared__ float w4s[8 * GSTRIDE];
    __shared__ float w2b[8][20];
    __shared__ float w3b[8][20];

    float4 c4v[16];
    #pragma unroll
    for (int r4 = 0; r4 < 16; ++r4)
        c4v[r4] = *(const float4*)(c4 + (r4 << 6) + ((l & 15) << 2));

    {
        const int i0 = (v >> 11) & 31, i1 = (v >> 6) & 31;
        float w2r = 0.f;
        #pragma unroll
        for (int r1 = 0; r1 < 16; ++r1)
            w2r = fmaf(c0[i0 * 16 + r1], c1[(r1 * 32 + i1) * 16 + r], w2r);
        w2b[tl][r] = w2r;
    }
    float4 w2v[4];
    #pragma unroll
    for (int q = 0; q < 4; ++q)
        w2v[q] = *(const float4*)&w2b[tl][q << 2];
    {
        const int i2 = (v >> 1) & 31;
        float w3r = 0.f;
        #pragma unroll
        for (int q = 0; q < 4; ++q) {
            w3r = fmaf(w2v[q].x, c2[((q * 4 + 0) * 32 + i2) * 16 + r], w3r);
            w3r = fmaf(w2v[q].y, c2[((q * 4 + 1) * 32 + i2) * 16 + r], w3r);
            w3r = fmaf(w2v[q].z, c2[((q * 4 + 2) * 32 + i2) * 16 + r], w3r);
            w3r = fmaf(w2v[q].w, c2[((q * 4 + 3) * 32 + i2) * 16 + r], w3r);
        }
        w3b[tl][r] = w3r;
    }
    float4 w3v[4];
    #pragma unroll
    for (int q = 0; q < 4; ++q)
        w3v[q] = *(const float4*)&w3b[tl][q << 2];
    {
        const int vlow16 = (v & 1) << 4;
        float4 a0 = {0,0,0,0}, a1 = {0,0,0,0};
        const float wv_arr0[16] = {w3v[0].x, w3v[0].y, w3v[0].z, w3v[0].w,
                                   w3v[1].x, w3v[1].y, w3v[1].z, w3v[1].w,
                                   w3v[2].x, w3v[2].y, w3v[2].z, w3v[2].w,
                                   w3v[3].x, w3v[3].y, w3v[3].z, w3v[3].w};
        #pragma unroll
        for (int r3 = 0; r3 < 16; ++r3) {
            const float wv = wv_arr0[r3];
            const float* base = c3 + ((r3 * 32 + vlow16) << 4);
            const float4 b0 = *(const float4*)(base + (l32 << 2));
            const float4 b1 = *(const float4*)(base + 128 + (l32 << 2));
            a0.x = fmaf(wv, b0.x, a0.x); a0.y = fmaf(wv, b0.y, a0.y);
            a0.z = fmaf(wv, b0.z, a0.z); a0.w = fmaf(wv, b0.w, a0.w);
            a1.x = fmaf(wv, b1.x, a1.x); a1.y = fmaf(wv, b1.y, a1.y);
            a1.z = fmaf(wv, b1.z, a1.z); a1.w = fmaf(wv, b1.w, a1.w);
        }
        float* sb = &w4s[tl * GSTRIDE + ((l32 & 3) << 2)];
        *(float4*)(sb + ((l32 >> 2)    ) * RSTRIDE) = a0;
        *(float4*)(sb + (8 + (l32 >> 2)) * RSTRIDE) = a1;
    }
    #pragma unroll
    for (int s = 0; s < 2; ++s) {
        const int slot = 2 * wid + s;
        const int tok  = blockIdx.x * 8 + slot;
        const float* slab = &w4s[slot * GSTRIDE];
        const int sub = l >> 4;
        const int colb = (l & 15) << 2;
        #pragma unroll
        for (int j = 0; j < 4; ++j) {
            const int row = (j << 2) + sub;
            const float* rp = slab + row * RSTRIDE;
            const float4 wa = *(const float4*)(rp);
            const float4 wb = *(const float4*)(rp + 4);
            const float4 wc = *(const float4*)(rp + 8);
            const float4 wd = *(const float4*)(rp + 12);
            float4 acc = {0,0,0,0};
            #define FB4(WV, K)                           \
                acc.x = fmaf(WV, c4v[K].x, acc.x);       \
                acc.y = fmaf(WV, c4v[K].y, acc.y);       \
                acc.z = fmaf(WV, c4v[K].z, acc.z);       \
                acc.w = fmaf(WV, c4v[K].w, acc.w);
            FB4(wa.x,  0) FB4(wa.y,  1) FB4(wa.z,  2) FB4(wa.w,  3)
            FB4(wb.x,  4) FB4(wb.y,  5) FB4(wb.z,  6) FB4(wb.w,  7)
            FB4(wc.x,  8) FB4(wc.y,  9) FB4(wc.z, 10) FB4(wc.w, 11)
            FB4(wd.x, 12) FB4(wd.y, 13) FB4(wd.z, 14) FB4(wd.w, 15)
            #undef FB4
            if (tok < n_tokens)
                __builtin_nontemporal_store(*(const f32x4*)&acc,
                    (f32x4*)(out + (size_t)tok * 1024 + (row << 6) + colb));
        }
    }
}

extern "C" void kernel_launch(void* const* d_in, const int* in_sizes, int n_in,
                              void* d_out, int out_size, void* d_ws, size_t ws_size,
                              hipStream_t stream) {
    const float* c0  = (const float*)d_in[0];
    const float* c1  = (const float*)d_in[1];
    const float* c2  = (const float*)d_in[2];
    const float* c3  = (const float*)d_in[3];
    const float* c4  = (const float*)d_in[4];
    const int*   idx = (const int*)d_in[5];
    float* out = (float*)d_out;

    const int n_tokens = in_sizes[5];                       // 16384
    const size_t ws_needed = 65536 + 256;

    if (ws_size >= ws_needed) {
        unsigned short* mfrag = (unsigned short*)d_ws;
        const int ngrp = (n_tokens + 15) / 16;              // 1024
        tt_mfrag<<<128, 256, 0, stream>>>(c3, c4, mfrag);
        tt_fused_expand<<<ngrp, 256, 0, stream>>>(c0, c1, c2, idx, mfrag,
                                                  out, n_tokens);
    } else {
        const int grid = (n_tokens + 7) / 8;
        tt_embed_fused<<<grid, 256, 0, stream>>>(c0, c1, c2, c3, c4, idx, out,
                                                 n_tokens);
    }
}

// Round 20
// 29.061 us; speedup vs baseline: 1.1059x; 1.0353x over previous
//
#include <hip/hip_runtime.h>
#include <hip/hip_bf16.h>

// TT embedding: vocab 65536, dim 1024, rank 16.
// out[v,d] = sum_{r1..r4} c0[0,i0,r1] c1[r1,i1,r2] c2[r2,i2,r3] c3[r3,i3,r4] c4[r4,i4,0]
//   i0=v>>11, i1=(v>>6)&31, i2=(v>>1)&31, i3=(v&1)*16+(d>>6), i4=d&63
//
// R19 lesson: MFMA algebra correct (absmax 9.3e-10) but no operand reuse:
// every block re-read the whole 64KB mfrag for 16 tokens. R20 restructures
// as the GEMM it is (C[16384x32] x M[32x1024], K=32):
//  prep (1 launch): blocks 0-127 -> mfrag (M in A-fragment order);
//                   blocks 128+  -> stages 1-2, pack w3ext in B-FRAGMENT
//                   order w3xf[group][lane]=uint4 (LDS transpose, 1KB store).
//  expand: wave = d-quarter holding ALL 16 A-frags in 64 VGPRs (16KB read
//          once, reused by every token group); per 16-token group: 1
//          coalesced b128 Wf load + 16 MFMA + 16 full-line stores.
//          2 groups/block, Wf prefetched; grid 512; ~90 VGPR.
// Fragment mappings identical to R18/R19 (HW-verified by absmax):
//   A: lane l, elem i -> k = 4*(l>>4)+(i&3)+16*(i>>2), row d = l&15
//   B (uint4): x,y = w3e[col][2g],[2g+1] (k=4g..4g+3); z,w = [8+2g],[8+2g+1]
//   C/D: col = l&15 (token), row = (l>>4)*4 + reg (d within tile)

typedef float f32x4 __attribute__((ext_vector_type(4)));
typedef short bf16x8 __attribute__((ext_vector_type(8)));

static __device__ __forceinline__ unsigned short f2bf(float x) {
    __hip_bfloat16 h = __float2bfloat16(x);
    return *reinterpret_cast<unsigned short*>(&h);
}

// ---------------- prep: mfrag (blocks 0-127) + w3xf (blocks 128+) ----------
__global__ __launch_bounds__(256) void tt_prep(
    const float* __restrict__ c0, const float* __restrict__ c1,
    const float* __restrict__ c2, const float* __restrict__ c3,
    const float* __restrict__ c4, const int* __restrict__ idx,
    unsigned short* __restrict__ mfrag,   // 32768 bf16 (A-frag order)
    unsigned char*  __restrict__ w3xf,    // ngrp * 1KB  (B-frag order)
    int n_tokens)
{
    const int t = threadIdx.x;

    if (blockIdx.x < 128) {
        // ---- M fragment precompute: M[k][d] = sum_r4 c3[r3][i3][r4]*c4[r4][i4]
        const int tid  = blockIdx.x * 256 + t;     // 0..32767
        const int tile = tid >> 9;
        const int lane = (tid >> 3) & 63;
        const int i    = tid & 7;
        const int k = 4 * (lane >> 4) + (i & 3) + ((i >> 2) << 4);
        const int d = (tile << 4) + (lane & 15);
        const int r3 = k & 15;
        const int b  = k >> 4;
        const int i3 = (b << 4) + (d >> 6);
        const int i4 = d & 63;
        float acc = 0.f;
        #pragma unroll
        for (int r4 = 0; r4 < 16; ++r4)
            acc = fmaf(c3[(r3 * 32 + i3) * 16 + r4], c4[(r4 << 6) + i4], acc);
        mfrag[tid] = f2bf(acc);
        return;
    }

    // ---- w3 part: 16 tokens/block, stages 1-2, pack B-fragments
    const int gb = blockIdx.x - 128;     // token group
    const int tl = t >> 4;               // token slot
    const int r  = t & 15;
    const int token = gb * 16 + tl;
    const int v = (token < n_tokens) ? idx[token] : 0;

    __shared__ float w2b[16][20];
    __shared__ float w3b[16][20];
    __shared__ unsigned int w3e[16][18];

    // Stage 1 (16-lane group = same wave; no barrier)
    {
        const int i0 = (v >> 11) & 31;
        const int i1 = (v >> 6) & 31;
        float w2r = 0.f;
        #pragma unroll
        for (int r1 = 0; r1 < 16; ++r1)
            w2r = fmaf(c0[i0 * 16 + r1], c1[(r1 * 32 + i1) * 16 + r], w2r);
        w2b[tl][r] = w2r;
    }
    float4 w2v[4];
    #pragma unroll
    for (int q = 0; q < 4; ++q)
        w2v[q] = *(const float4*)&w2b[tl][q << 2];

    // Stage 2 (r2 order 0..15)
    {
        const int i2 = (v >> 1) & 31;
        float w3r = 0.f;
        #pragma unroll
        for (int q = 0; q < 4; ++q) {
            w3r = fmaf(w2v[q].x, c2[((q * 4 + 0) * 32 + i2) * 16 + r], w3r);
            w3r = fmaf(w2v[q].y, c2[((q * 4 + 1) * 32 + i2) * 16 + r], w3r);
            w3r = fmaf(w2v[q].z, c2[((q * 4 + 2) * 32 + i2) * 16 + r], w3r);
            w3r = fmaf(w2v[q].w, c2[((q * 4 + 3) * 32 + i2) * 16 + r], w3r);
        }
        w3b[tl][r] = w3r;
    }
    // pack bf16 pair uints, zeroed outside vlow half
    {
        const int vlow = v & 1;
        const int k0 = 2 * r, k1 = 2 * r + 1;
        const unsigned int lo = ((k0 >> 4) == vlow) ? f2bf(w3b[tl][k0 & 15]) : 0u;
        const unsigned int hi = ((k1 >> 4) == vlow) ? f2bf(w3b[tl][k1 & 15]) : 0u;
        w3e[tl][r] = lo | (hi << 16);
    }

    __syncthreads();

    // transpose to B-fragment order: lane l=(g,col) -> uint4, 1KB coalesced
    if (t < 64) {
        const int col = t & 15, g = t >> 4;
        uint4 wf;
        wf.x = w3e[col][2 * g];
        wf.y = w3e[col][2 * g + 1];
        wf.z = w3e[col][8 + 2 * g];
        wf.w = w3e[col][8 + 2 * g + 1];
        *(uint4*)(w3xf + (size_t)gb * 1024 + t * 16) = wf;
    }
}

// ---------------- expand: A-frags resident, 2 token groups per block -------
__global__ __launch_bounds__(256) void tt_expand(
    const unsigned short* __restrict__ mfrag,
    const unsigned char*  __restrict__ w3xf,
    float* __restrict__ out, int n_tokens, int ngrp)
{
    const int t = threadIdx.x;
    const int w = t >> 6;            // d-quarter
    const int l = t & 63;
    const int col = l & 15;
    const int g   = l >> 4;

    // all 16 A-fragments of this quarter: 64 VGPR, read once, reused forever
    bf16x8 mf[16];
    #pragma unroll
    for (int n = 0; n < 16; ++n)
        mf[n] = *(const bf16x8*)(mfrag + (((w << 4) + n) << 9) + (l << 3));

    const int g0 = blockIdx.x * 2;
    const int g1c = (g0 + 1 < ngrp) ? (g0 + 1) : (ngrp - 1);

    // prefetch both B-fragments (coalesced 1KB loads)
    const bf16x8 bfa = *(const bf16x8*)(w3xf + (size_t)g0  * 1024 + l * 16);
    const bf16x8 bfb = *(const bf16x8*)(w3xf + (size_t)g1c * 1024 + l * 16);

    #pragma unroll
    for (int s = 0; s < 2; ++s) {
        const int grp = g0 + s;
        if (grp >= ngrp) break;
        const bf16x8 bf = s ? bfb : bfa;
        const int tok = grp * 16 + col;
        const bool ok = (tok < n_tokens);
        float* outp = out + (size_t)tok * 1024 + (w << 8) + (g << 2);

        #pragma unroll
        for (int n = 0; n < 16; ++n) {
            f32x4 acc = {0.f, 0.f, 0.f, 0.f};
            acc = __builtin_amdgcn_mfma_f32_16x16x32_bf16(mf[n], bf, acc, 0, 0, 0);
            if (ok)
                __builtin_nontemporal_store(acc, (f32x4*)(outp + (n << 4)));
        }
    }
}

// ---------------- Fallback: R16 fused scalar kernel (proven) ---------------
#define RSTRIDE 20
#define GSTRIDE 328

__global__ __launch_bounds__(256) void tt_embed_fused(
    const float* __restrict__ c0, const float* __restrict__ c1,
    const float* __restrict__ c2, const float* __restrict__ c3,
    const float* __restrict__ c4, const int* __restrict__ idx,
    float* __restrict__ out, int n_tokens)
{
    const int t   = threadIdx.x;
    const int tl  = t >> 5;
    const int l32 = t & 31;
    const int r   = t & 15;
    const int l   = t & 63;
    const int wid = t >> 6;
    const int token = blockIdx.x * 8 + tl;
    const int v = (token < n_tokens) ? idx[token] : 0;

    __shared__ float w4s[8 * GSTRIDE];
    __shared__ float w2b[8][20];
    __shared__ float w3b[8][20];

    float4 c4v[16];
    #pragma unroll
    for (int r4 = 0; r4 < 16; ++r4)
        c4v[r4] = *(const float4*)(c4 + (r4 << 6) + ((l & 15) << 2));

    {
        const int i0 = (v >> 11) & 31, i1 = (v >> 6) & 31;
        float w2r = 0.f;
        #pragma unroll
        for (int r1 = 0; r1 < 16; ++r1)
            w2r = fmaf(c0[i0 * 16 + r1], c1[(r1 * 32 + i1) * 16 + r], w2r);
        w2b[tl][r] = w2r;
    }
    float4 w2v[4];
    #pragma unroll
    for (int q = 0; q < 4; ++q)
        w2v[q] = *(const float4*)&w2b[tl][q << 2];
    {
        const int i2 = (v >> 1) & 31;
        float w3r = 0.f;
        #pragma unroll
        for (int q = 0; q < 4; ++q) {
            w3r = fmaf(w2v[q].x, c2[((q * 4 + 0) * 32 + i2) * 16 + r], w3r);
            w3r = fmaf(w2v[q].y, c2[((q * 4 + 1) * 32 + i2) * 16 + r], w3r);
            w3r = fmaf(w2v[q].z, c2[((q * 4 + 2) * 32 + i2) * 16 + r], w3r);
            w3r = fmaf(w2v[q].w, c2[((q * 4 + 3) * 32 + i2) * 16 + r], w3r);
        }
        w3b[tl][r] = w3r;
    }
    float4 w3v[4];
    #pragma unroll
    for (int q = 0; q < 4; ++q)
        w3v[q] = *(const float4*)&w3b[tl][q << 2];
    {
        const int vlow16 = (v & 1) << 4;
        float4 a0 = {0,0,0,0}, a1 = {0,0,0,0};
        const float wv_arr0[16] = {w3v[0].x, w3v[0].y, w3v[0].z, w3v[0].w,
                                   w3v[1].x, w3v[1].y, w3v[1].z, w3v[1].w,
                                   w3v[2].x, w3v[2].y, w3v[2].z, w3v[2].w,
                                   w3v[3].x, w3v[3].y, w3v[3].z, w3v[3].w};
        #pragma unroll
        for (int r3 = 0; r3 < 16; ++r3) {
            const float wv = wv_arr0[r3];
            const float* base = c3 + ((r3 * 32 + vlow16) << 4);
            const float4 b0 = *(const float4*)(base + (l32 << 2));
            const float4 b1 = *(const float4*)(base + 128 + (l32 << 2));
            a0.x = fmaf(wv, b0.x, a0.x); a0.y = fmaf(wv, b0.y, a0.y);
            a0.z = fmaf(wv, b0.z, a0.z); a0.w = fmaf(wv, b0.w, a0.w);
            a1.x = fmaf(wv, b1.x, a1.x); a1.y = fmaf(wv, b1.y, a1.y);
            a1.z = fmaf(wv, b1.z, a1.z); a1.w = fmaf(wv, b1.w, a1.w);
        }
        float* sb = &w4s[tl * GSTRIDE + ((l32 & 3) << 2)];
        *(float4*)(sb + ((l32 >> 2)    ) * RSTRIDE) = a0;
        *(float4*)(sb + (8 + (l32 >> 2)) * RSTRIDE) = a1;
    }
    #pragma unroll
    for (int s = 0; s < 2; ++s) {
        const int slot = 2 * wid + s;
        const int tok  = blockIdx.x * 8 + slot;
        const float* slab = &w4s[slot * GSTRIDE];
        const int sub = l >> 4;
        const int colb = (l & 15) << 2;
        #pragma unroll
        for (int j = 0; j < 4; ++j) {
            const int row = (j << 2) + sub;
            const float* rp = slab + row * RSTRIDE;
            const float4 wa = *(const float4*)(rp);
            const float4 wb = *(const float4*)(rp + 4);
            const float4 wc = *(const float4*)(rp + 8);
            const float4 wd = *(const float4*)(rp + 12);
            float4 acc = {0,0,0,0};
            #define FB4(WV, K)                           \
                acc.x = fmaf(WV, c4v[K].x, acc.x);       \
                acc.y = fmaf(WV, c4v[K].y, acc.y);       \
                acc.z = fmaf(WV, c4v[K].z, acc.z);       \
                acc.w = fmaf(WV, c4v[K].w, acc.w);
            FB4(wa.x,  0) FB4(wa.y,  1) FB4(wa.z,  2) FB4(wa.w,  3)
            FB4(wb.x,  4) FB4(wb.y,  5) FB4(wb.z,  6) FB4(wb.w,  7)
            FB4(wc.x,  8) FB4(wc.y,  9) FB4(wc.z, 10) FB4(wc.w, 11)
            FB4(wd.x, 12) FB4(wd.y, 13) FB4(wd.z, 14) FB4(wd.w, 15)
            #undef FB4
            if (tok < n_tokens)
                __builtin_nontemporal_store(*(const f32x4*)&acc,
                    (f32x4*)(out + (size_t)tok * 1024 + (row << 6) + colb));
        }
    }
}

extern "C" void kernel_launch(void* const* d_in, const int* in_sizes, int n_in,
                              void* d_out, int out_size, void* d_ws, size_t ws_size,
                              hipStream_t stream) {
    const float* c0  = (const float*)d_in[0];
    const float* c1  = (const float*)d_in[1];
    const float* c2  = (const float*)d_in[2];
    const float* c3  = (const float*)d_in[3];
    const float* c4  = (const float*)d_in[4];
    const int*   idx = (const int*)d_in[5];
    float* out = (float*)d_out;

    const int n_tokens = in_sizes[5];                       // 16384
    const int ngrp = (n_tokens + 15) / 16;                  // 1024
    const size_t ws_needed = 65536 + (size_t)ngrp * 1024 + 256;

    if (ws_size >= ws_needed) {
        unsigned short* mfrag = (unsigned short*)d_ws;
        unsigned char*  w3xf  = (unsigned char*)d_ws + 65536;
        tt_prep<<<128 + ngrp, 256, 0, stream>>>(c0, c1, c2, c3, c4, idx,
                                                mfrag, w3xf, n_tokens);
        tt_expand<<<(ngrp + 1) / 2, 256, 0, stream>>>(mfrag, w3xf, out,
                                                      n_tokens, ngrp);
    } else {
        const int grid = (n_tokens + 7) / 8;
        tt_embed_fused<<<grid, 256, 0, stream>>>(c0, c1, c2, c3, c4, idx, out,
                                                 n_tokens);
    }
}

// Round 21
// 24.554 us; speedup vs baseline: 1.3088x; 1.1835x over previous
//
#include <hip/hip_runtime.h>
#include <hip/hip_bf16.h>

// TT embedding: vocab 65536, dim 1024, rank 16.
// out[v,d] = sum_{r1..r4} c0[0,i0,r1] c1[r1,i1,r2] c2[r2,i2,r3] c3[r3,i3,r4] c4[r4,i4,0]
//   i0=v>>11, i1=(v>>6)&31, i2=(v>>1)&31, i3=(v&1)*16+(d>>6), i4=d&63
//
// FINAL (R21 = resubmission of R17, session best: 24.4us, absmax 0.0).
// Session summary: 10 structures (scalar gather/coalesced, per-wave, split,
// fused, software-pipelined, 3x MFMA-GEMM) all land 24-30us with every pipe
// <50% (probe: VALU 33%, occ 65%, conflicts 0, HBM idle; time invariant to
// L3-vs-HBM write placement). Structure here: 8 tokens/wave as 4 pairs;
// S123(pair i+1) interleaved chunk-by-chunk with stage4(pair i) through
// double-buffered wave-private LDS slabs; zero barriers.

typedef float f32x4 __attribute__((ext_vector_type(4)));

#define RSTRIDE 20
#define BUFSTRIDE (2 * 16 * RSTRIDE)          // one buf = 2 tokens x 16 rows
#define WSLAB (2 * BUFSTRIDE + 8)             // per-wave slab (+8: bank stagger)

#define FMA4(WV, K)                              \
    acc.x = fmaf(WV, c4v[K].x, acc.x);           \
    acc.y = fmaf(WV, c4v[K].y, acc.y);           \
    acc.z = fmaf(WV, c4v[K].z, acc.z);           \
    acc.w = fmaf(WV, c4v[K].w, acc.w);

// stage-4 chunk: one row-quad of token (PB+S) from buf BUF
#define PC(BUF, S, J, PB) {                                                   \
    const int tok_ = (PB) + (S);                                              \
    const float* rp = myslab + (BUF) * BUFSTRIDE + (S) * (16 * RSTRIDE)       \
                      + (4 * (J) + sub) * RSTRIDE;                            \
    const float4 qa = *(const float4*)(rp);                                   \
    const float4 qb = *(const float4*)(rp + 4);                               \
    const float4 qc = *(const float4*)(rp + 8);                               \
    const float4 qd = *(const float4*)(rp + 12);                              \
    float4 acc = {0, 0, 0, 0};                                                \
    FMA4(qa.x,  0) FMA4(qa.y,  1) FMA4(qa.z,  2) FMA4(qa.w,  3)               \
    FMA4(qb.x,  4) FMA4(qb.y,  5) FMA4(qb.z,  6) FMA4(qb.w,  7)               \
    FMA4(qc.x,  8) FMA4(qc.y,  9) FMA4(qc.z, 10) FMA4(qc.w, 11)               \
    FMA4(qd.x, 12) FMA4(qd.y, 13) FMA4(qd.z, 14) FMA4(qd.w, 15)               \
    if (tok_ < n_tokens)                                                      \
        __builtin_nontemporal_store(*(const f32x4*)&acc,                      \
            (f32x4*)(out + (size_t)tok_ * 1024 + ((4 * (J) + sub) << 6) + colb)); }

// stage 1: w2 + LDS round-trip into w2v* registers
#define N_S1(VV, BUF) {                                                       \
    const int i0 = ((VV) >> 11) & 31, i1 = ((VV) >> 6) & 31;                  \
    const float* c0b = c0 + i0 * 16;                                          \
    const float* c1b = c1 + i1 * 16 + r;                                      \
    w2r = 0.f;                                                                \
    w2r = fmaf(c0b[ 0], c1b[ 0 * 512], w2r);                                  \
    w2r = fmaf(c0b[ 1], c1b[ 1 * 512], w2r);                                  \
    w2r = fmaf(c0b[ 2], c1b[ 2 * 512], w2r);                                  \
    w2r = fmaf(c0b[ 3], c1b[ 3 * 512], w2r);                                  \
    w2r = fmaf(c0b[ 4], c1b[ 4 * 512], w2r);                                  \
    w2r = fmaf(c0b[ 5], c1b[ 5 * 512], w2r);                                  \
    w2r = fmaf(c0b[ 6], c1b[ 6 * 512], w2r);                                  \
    w2r = fmaf(c0b[ 7], c1b[ 7 * 512], w2r);                                  \
    w2r = fmaf(c0b[ 8], c1b[ 8 * 512], w2r);                                  \
    w2r = fmaf(c0b[ 9], c1b[ 9 * 512], w2r);                                  \
    w2r = fmaf(c0b[10], c1b[10 * 512], w2r);                                  \
    w2r = fmaf(c0b[11], c1b[11 * 512], w2r);                                  \
    w2r = fmaf(c0b[12], c1b[12 * 512], w2r);                                  \
    w2r = fmaf(c0b[13], c1b[13 * 512], w2r);                                  \
    w2r = fmaf(c0b[14], c1b[14 * 512], w2r);                                  \
    w2r = fmaf(c0b[15], c1b[15 * 512], w2r);                                  \
    w23[wid][BUF][0][tl2][r] = w2r;                                           \
    w2v0 = *(const float4*)&w23[wid][BUF][0][tl2][0];                         \
    w2v1 = *(const float4*)&w23[wid][BUF][0][tl2][4];                         \
    w2v2 = *(const float4*)&w23[wid][BUF][0][tl2][8];                         \
    w2v3 = *(const float4*)&w23[wid][BUF][0][tl2][12];                        \
    sa0 = (float4){0, 0, 0, 0};                                               \
    sa1 = (float4){0, 0, 0, 0}; }

// stage 2: w3 + LDS round-trip into w3v* registers (r2 order 0..15)
#define N_S2(VV, BUF) {                                                       \
    const int i2 = ((VV) >> 1) & 31;                                          \
    const float* c2b = c2 + i2 * 16 + r;                                      \
    w3r = 0.f;                                                                \
    w3r = fmaf(w2v0.x, c2b[ 0 * 512], w3r);                                   \
    w3r = fmaf(w2v0.y, c2b[ 1 * 512], w3r);                                   \
    w3r = fmaf(w2v0.z, c2b[ 2 * 512], w3r);                                   \
    w3r = fmaf(w2v0.w, c2b[ 3 * 512], w3r);                                   \
    w3r = fmaf(w2v1.x, c2b[ 4 * 512], w3r);                                   \
    w3r = fmaf(w2v1.y, c2b[ 5 * 512], w3r);                                   \
    w3r = fmaf(w2v1.z, c2b[ 6 * 512], w3r);                                   \
    w3r = fmaf(w2v1.w, c2b[ 7 * 512], w3r);                                   \
    w3r = fmaf(w2v2.x, c2b[ 8 * 512], w3r);                                   \
    w3r = fmaf(w2v2.y, c2b[ 9 * 512], w3r);                                   \
    w3r = fmaf(w2v2.z, c2b[10 * 512], w3r);                                   \
    w3r = fmaf(w2v2.w, c2b[11 * 512], w3r);                                   \
    w3r = fmaf(w2v3.x, c2b[12 * 512], w3r);                                   \
    w3r = fmaf(w2v3.y, c2b[13 * 512], w3r);                                   \
    w3r = fmaf(w2v3.z, c2b[14 * 512], w3r);                                   \
    w3r = fmaf(w2v3.w, c2b[15 * 512], w3r);                                   \
    w23[wid][BUF][1][tl2][r] = w3r;                                           \
    w3v0 = *(const float4*)&w23[wid][BUF][1][tl2][0];                         \
    w3v1 = *(const float4*)&w23[wid][BUF][1][tl2][4];                         \
    w3v2 = *(const float4*)&w23[wid][BUF][1][tl2][8];                         \
    w3v3 = *(const float4*)&w23[wid][BUF][1][tl2][12];                        \
}

#define S3STEP(W, OFF) {                                                      \
    const float4 b0 = *(const float4*)(c3b + (OFF));                          \
    const float4 b1 = *(const float4*)(c3b + (OFF) + 128);                    \
    sa0.x = fmaf(W, b0.x, sa0.x); sa0.y = fmaf(W, b0.y, sa0.y);               \
    sa0.z = fmaf(W, b0.z, sa0.z); sa0.w = fmaf(W, b0.w, sa0.w);               \
    sa1.x = fmaf(W, b1.x, sa1.x); sa1.y = fmaf(W, b1.y, sa1.y);               \
    sa1.z = fmaf(W, b1.z, sa1.z); sa1.w = fmaf(W, b1.w, sa1.w); }

// stage-3 quarter: r3 = R3B..R3B+3 with weights W0..W3
#define N_S3Q(VV, W0, W1, W2, W3, R3B) {                                      \
    const float* c3b = c3 + (((VV) & 1) << 8) + (l32 << 2);                   \
    S3STEP(W0, ((R3B) + 0) * 512)                                             \
    S3STEP(W1, ((R3B) + 1) * 512)                                             \
    S3STEP(W2, ((R3B) + 2) * 512)                                             \
    S3STEP(W3, ((R3B) + 3) * 512) }

#define N_SCATTER(BUF) {                                                      \
    float* sb = myslab + (BUF) * BUFSTRIDE + tl2 * (16 * RSTRIDE)             \
                + ((l32 & 3) << 2);                                           \
    *(float4*)(sb + (l32 >> 2) * RSTRIDE) = sa0;                              \
    *(float4*)(sb + (8 + (l32 >> 2)) * RSTRIDE) = sa1; }

__global__ __launch_bounds__(256) void tt_embed_kernel(
    const float* __restrict__ c0,   // 32*16
    const float* __restrict__ c1,   // 16*32*16
    const float* __restrict__ c2,   // 16*32*16
    const float* __restrict__ c3,   // 16*32*16
    const float* __restrict__ c4,   // 16*64
    const int*   __restrict__ idx,  // n_tokens
    float*       __restrict__ out,  // n_tokens x 1024
    int n_tokens)
{
    const int t    = threadIdx.x;
    const int wid  = t >> 6;          // wave in block
    const int l    = t & 63;
    const int tl2  = (t >> 5) & 1;    // token half within wave
    const int l32  = t & 31;
    const int r    = t & 15;
    const int sub  = l >> 4;          // stage-4 row sub-index
    const int colb = (l & 15) << 2;   // stage-4 col base

    __shared__ float w4s[4 * WSLAB];            // ~20.6 KB
    __shared__ float w23[4][2][2][2][20];       // ~2.6 KB

    const int wb = (blockIdx.x * 4 + wid) * 8;  // wave's 8-token base
    float* const myslab = &w4s[wid * WSLAB];

    // c4 slice (64 VGPR), reused for all 8 tokens
    float4 c4v[16];
    #pragma unroll
    for (int r4 = 0; r4 < 16; ++r4)
        c4v[r4] = *(const float4*)(c4 + (r4 << 6) + colb);

    float w2r, w3r;
    float4 w2v0, w2v1, w2v2, w2v3;
    float4 w3v0, w3v1, w3v2, w3v3;
    float4 sa0, sa1;

    const int nclamp = n_tokens - 1;

    // ---- prologue: v for pairs 0 and 1; S123(pair 0) -> buf 0
    int a0i = wb + tl2;           if (a0i > nclamp) a0i = nclamp;
    int v0 = idx[a0i];
    int a1i = wb + 2 + tl2;       if (a1i > nclamp) a1i = nclamp;
    int vN = idx[a1i];

    N_S1(v0, 0) N_S2(v0, 0)
    N_S3Q(v0, w3v0.x, w3v0.y, w3v0.z, w3v0.w,  0)
    N_S3Q(v0, w3v1.x, w3v1.y, w3v1.z, w3v1.w,  4)
    N_S3Q(v0, w3v2.x, w3v2.y, w3v2.z, w3v2.w,  8)
    N_S3Q(v0, w3v3.x, w3v3.y, w3v3.z, w3v3.w, 12)
    N_SCATTER(0)

    // ---- main loop: stage4(pair it) interleaved with S123(pair it+1)
    for (int it = 0; it < 3; ++it) {
        const int cur = it & 1, nxt = cur ^ 1;
        const int pb = wb + 2 * it;

        int a2i = wb + 2 * (it + 2) + tl2;    // pair it+2 idx (clamped; unused
        if (a2i > nclamp) a2i = nclamp;       //  garbage on final lap is dead)
        const int vNN = idx[a2i];

        N_S1(vN, nxt)
        PC(cur, 0, 0, pb)
        PC(cur, 0, 1, pb)
        N_S2(vN, nxt)
        PC(cur, 0, 2, pb)
        PC(cur, 0, 3, pb)
        N_S3Q(vN, w3v0.x, w3v0.y, w3v0.z, w3v0.w,  0)
        PC(cur, 1, 0, pb)
        N_S3Q(vN, w3v1.x, w3v1.y, w3v1.z, w3v1.w,  4)
        PC(cur, 1, 1, pb)
        N_S3Q(vN, w3v2.x, w3v2.y, w3v2.z, w3v2.w,  8)
        PC(cur, 1, 2, pb)
        N_S3Q(vN, w3v3.x, w3v3.y, w3v3.z, w3v3.w, 12)
        N_SCATTER(nxt)
        PC(cur, 1, 3, pb)

        vN = vNN;
    }

    // ---- epilogue: stage4(pair 3) from buf 1
    {
        const int pb = wb + 6;
        PC(1, 0, 0, pb) PC(1, 0, 1, pb) PC(1, 0, 2, pb) PC(1, 0, 3, pb)
        PC(1, 1, 0, pb) PC(1, 1, 1, pb) PC(1, 1, 2, pb) PC(1, 1, 3, pb)
    }
}

extern "C" void kernel_launch(void* const* d_in, const int* in_sizes, int n_in,
                              void* d_out, int out_size, void* d_ws, size_t ws_size,
                              hipStream_t stream) {
    const float* c0  = (const float*)d_in[0];
    const float* c1  = (const float*)d_in[1];
    const float* c2  = (const float*)d_in[2];
    const float* c3  = (const float*)d_in[3];
    const float* c4  = (const float*)d_in[4];
    const int*   idx = (const int*)d_in[5];
    float* out = (float*)d_out;

    const int n_tokens = in_sizes[5];              // 8 * 2048 = 16384
    const int grid = (n_tokens + 31) / 32;         // 512 (8 tokens x 4 waves)
    tt_embed_kernel<<<grid, 256, 0, stream>>>(c0, c1, c2, c3, c4, idx, out, n_tokens);
}